// Round 8
// baseline (486.267 us; speedup 1.0000x reference)
//
#include <hip/hip_runtime.h>
#include <hip/hip_bf16.h>
#include <math.h>

#define D 128
#define NEG 0.2f
#define EPSV 1e-16f
#define NPB 20          // nodes per block (N=10000 -> exactly 500 blocks, ~2/CU, all co-resident)
#define GRP_N 5         // nodes per 128-col group in GEMV (4 groups * 5 = NPB)

// ---------------- CSR build (once per call; graph constant across layers) ----------------
// count is folded into linear0_kernel (saves a dispatch).
__global__ void scan_kernel(const int* __restrict__ deg, int N, int* __restrict__ row_ptr, int* __restrict__ cursor){
  __shared__ int part[1024];
  const int CH = 16;                 // 1024*16 = 16384 >= N
  int t = threadIdx.x;
  int base = t*CH;
  int local[CH]; int s = 0;
  #pragma unroll
  for (int j=0;j<CH;j++){ int idx=base+j; int v = (idx<N)? deg[idx] : 0; local[j]=s; s+=v; }
  part[t]=s; __syncthreads();
  for (int off=1; off<1024; off<<=1){
    int v = (t>=off)? part[t-off] : 0;
    __syncthreads();
    part[t]+=v;
    __syncthreads();
  }
  int cb = (t==0)? 0 : part[t-1];
  #pragma unroll
  for (int j=0;j<CH;j++){ int idx=base+j; if(idx<N){ int r=cb+local[j]; row_ptr[idx]=r; cursor[idx]=r; } }
  if (t==1023) row_ptr[N]=part[1023];
}

__global__ void scatter_kernel(const int* __restrict__ esrc, const int* __restrict__ edst,
                               int E, int N, int* __restrict__ cursor, int* __restrict__ csr_src){
  int i = blockIdx.x*blockDim.x + threadIdx.x;
  int tot = E + N;
  if (i>=tot) return;
  int s, d2;
  if (i<E){ s=esrc[i]; d2=edst[i]; } else { s=i-E; d2=i-E; }
  int pos = atomicAdd(&cursor[d2],1);
  csr_src[pos]=s;
}

// ---------------- GEMV phase: rbuf rows @ W -> h + es/ed ----------------
// 512 threads = 4 col-groups of 128; each group computes GRP_N nodes.
// Per k: 1 coalesced W load feeds GRP_N FMAs per thread. LDS row reads are
// wave-uniform broadcasts (16B/bank-set, conflict-free). h_out stores are
// NON-TEMPORAL: consumed next layer mostly by other XCDs, so keeping them
// out of the local L2 preserves h_cur residency for the gather.
template<int HNEXT>
__device__ __forceinline__ void gemv_phase(const float (*rbuf)[D], int nbase, int N,
                                           const float* __restrict__ Wn,
                                           const float* __restrict__ av_, const float* __restrict__ bv_,
                                           float* __restrict__ h_out, float* __restrict__ es_out,
                                           float* __restrict__ ed_out, float (*pE)[2], float (*pD)[2]){
  const int t   = threadIdx.x;
  const int col = t & (D-1);
  const int g   = t >> 7;                 // 0..3
  const float av = av_[col], bv = bv_[col];
  const float* __restrict__ r[GRP_N];
  #pragma unroll
  for (int j=0;j<GRP_N;j++) r[j] = rbuf[g*GRP_N + j];
  float acc[GRP_N];
  #pragma unroll
  for (int j=0;j<GRP_N;j++) acc[j]=0.f;

  #pragma unroll 4
  for (int k=0;k<D;k+=4){
    const float w0 = Wn[(size_t)(k+0)*D + col];
    const float w1 = Wn[(size_t)(k+1)*D + col];
    const float w2 = Wn[(size_t)(k+2)*D + col];
    const float w3 = Wn[(size_t)(k+3)*D + col];
    #pragma unroll
    for (int j=0;j<GRP_N;j++){
      const float4 xv = *reinterpret_cast<const float4*>(r[j] + k);
      acc[j] = fmaf(xv.w, w3, fmaf(xv.z, w2, fmaf(xv.y, w1, fmaf(xv.x, w0, acc[j]))));
    }
  }

  if constexpr (HNEXT==4){
    #pragma unroll
    for (int j=0;j<GRP_N;j++){
      const int n = nbase + g*GRP_N + j;
      if (n < N){                          // group-uniform
        __builtin_nontemporal_store(acc[j], &h_out[(size_t)n*D + col]);
        float ps = acc[j]*av, pd = acc[j]*bv;
        #pragma unroll
        for (int off=16; off; off>>=1){ ps += __shfl_xor(ps, off, 32); pd += __shfl_xor(pd, off, 32); }
        if ((col&31)==0){ es_out[n*4 + (col>>5)] = ps; ed_out[n*4 + (col>>5)] = pd; }
      }
    }
  } else {
    const int half = (t>>6)&1;
    #pragma unroll
    for (int j=0;j<GRP_N;j++){
      const int n = nbase + g*GRP_N + j;
      float ps = 0.f, pd = 0.f;
      if (n < N){
        __builtin_nontemporal_store(acc[j], &h_out[(size_t)n*D + col]);
        ps = acc[j]*av; pd = acc[j]*bv;
      }
      #pragma unroll
      for (int off=32; off; off>>=1){ ps += __shfl_xor(ps, off, 64); pd += __shfl_xor(pd, off, 64); }
      if ((t&63)==0){ pE[g*GRP_N+j][half]=ps; pD[g*GRP_N+j][half]=pd; }
    }
    __syncthreads();
    if (t < NPB){
      const int n = nbase + t;
      if (n < N){
        es_out[n] = pE[t][0]+pE[t][1];
        ed_out[n] = pD[t][0]+pD[t][1];
      }
    }
  }
}

// ---------------- Layer-0 linear (+ folded CSR degree count) ----------------
__launch_bounds__(512, 4)
__global__ void linear0_kernel(const float* __restrict__ x, const float* __restrict__ Wn,
                               const float* __restrict__ an_src, const float* __restrict__ an_dst,
                               int N, int E, const int* __restrict__ edst, int* __restrict__ deg,
                               float* __restrict__ h_out, float* __restrict__ es_out, float* __restrict__ ed_out){
  __shared__ float rbuf[NPB][D];
  __shared__ float pE[NPB][2], pD[NPB][2];
  const int t = threadIdx.x;
  const int nbase = blockIdx.x*NPB;
  // folded CSR count (deg pre-zeroed by memsetAsync)
  {
    const int gid = blockIdx.x*512 + t;
    const int gs  = gridDim.x*512;
    const int tot = E + N;
    for (int i = gid; i < tot; i += gs){
      const int d2 = (i < E) ? edst[i] : (i - E);
      atomicAdd(&deg[d2], 1);
    }
  }
  for (int i = t; i < NPB*(D/4); i += 512){
    const int row = i >> 5;            // i / 32
    const int cc  = (i & 31) * 4;
    int n = nbase + row; if (n > N-1) n = N-1;
    const float4 v = *reinterpret_cast<const float4*>(x + (size_t)n*D + cc);
    *reinterpret_cast<float4*>(&rbuf[row][cc]) = v;
  }
  __syncthreads();
  gemv_phase<4>(rbuf, nbase, N, Wn, an_src, an_dst, h_out, es_out, ed_out, pE, pD);
}

// ---------------- Fused: aggregate(layer l, heads=4) + linear(layer l+1) ----------------
// Aggregate: waves pull nodes from a per-block LDS queue (perfect balance under
// degree variance). Per 64-edge tile: phase A lanes gather csr+es, exp -> sIdx (s*D)
// + packed sP[4] in LDS. Phase B: half-wave edge split -- 32 lanes x float4 = one full
// h row per instruction, 2 edges/iter, unroll 8. Single-pass softmax (exp<=e^80),
// half partials combined via shfl_xor(32). Result row (bias+relu) -> rbuf.
// GEMV: NPB aggregated rows @ next layer's W + attention dots.
template<int HNEXT>
__launch_bounds__(512, 4)
__global__ void fused_kernel(const float* __restrict__ h, const float* __restrict__ es, const float* __restrict__ ed,
                             const int* __restrict__ row_ptr, const int* __restrict__ csr_src,
                             const float* __restrict__ bias,
                             const float* __restrict__ Wn, const float* __restrict__ an_src, const float* __restrict__ an_dst,
                             int N, float* __restrict__ h_out, float* __restrict__ es_out, float* __restrict__ ed_out){
  __shared__ int   sIdx[8][64];      // 2 KB  (premultiplied: s*D)
  __shared__ float sP[8][64][4];     // 8 KB  (p per head, packed float4 per edge)
  __shared__ float rbuf[NPB][D];     // 10 KB
  __shared__ float pE[NPB][2], pD[NPB][2];
  __shared__ int qhead;
  const int t = threadIdx.x;
  const int lane = t & 63;
  const int wid  = t >> 6;
  const int nbase = blockIdx.x*NPB;
  const int half = lane >> 5;
  const int l32  = lane & 31;
  const int cq   = l32 * 4;          // my 4 channels
  const int myh4 = l32 >> 3;         // my head

  if (t == 0) qhead = 8;
  __syncthreads();

  int local = wid;
  while (local < NPB){
    const int n = nbase + local;
    if (n >= N){
      if (half == 0) *reinterpret_cast<float4*>(&rbuf[local][cq]) = make_float4(0.f,0.f,0.f,0.f);
    } else {
      const int start = row_ptr[n], end = row_ptr[n+1];
      const float ed0 = ed[n*4+0], ed1 = ed[n*4+1], ed2 = ed[n*4+2], ed3 = ed[n*4+3];
      float4 acc = make_float4(0.f,0.f,0.f,0.f);
      float zph = 0.f;

      for (int t0 = start; t0 < end; t0 += 64){
        const int cnt = min(64, end - t0);
        // --- phase A: edge-parallel p computation (zero-padded beyond cnt) ---
        {
          int sOff = 0; float p0=0.f,p1=0.f,p2=0.f,p3=0.f;
          if (lane < cnt){
            const int s = csr_src[t0 + lane];
            sOff = s*D;
            const float4 e4 = *reinterpret_cast<const float4*>(es + (size_t)s*4);
            float q0 = e4.x + ed0; q0 = (q0>=0.f)? q0 : NEG*q0; q0 = fminf(q0, 80.f);
            float q1 = e4.y + ed1; q1 = (q1>=0.f)? q1 : NEG*q1; q1 = fminf(q1, 80.f);
            float q2 = e4.z + ed2; q2 = (q2>=0.f)? q2 : NEG*q2; q2 = fminf(q2, 80.f);
            float q3 = e4.w + ed3; q3 = (q3>=0.f)? q3 : NEG*q3; q3 = fminf(q3, 80.f);
            p0 = __expf(q0); p1 = __expf(q1); p2 = __expf(q2); p3 = __expf(q3);
          }
          sIdx[wid][lane] = sOff;
          *reinterpret_cast<float4*>(&sP[wid][lane][0]) = make_float4(p0,p1,p2,p3);
        }
        // --- phase B: 2 edges/iter (one per half-wave), full row per instruction ---
        const int cr = (cnt + 1) & ~1;
        #pragma unroll 8
        for (int e = 0; e < cr; e += 2){
          const int   off = sIdx[wid][e + half];
          const float p   = sP[wid][e + half][myh4];
          const float4 hv = *reinterpret_cast<const float4*>(h + (size_t)off + cq);
          zph += p;
          acc.x = fmaf(p, hv.x, acc.x);
          acc.y = fmaf(p, hv.y, acc.y);
          acc.z = fmaf(p, hv.z, acc.z);
          acc.w = fmaf(p, hv.w, acc.w);
        }
      }
      // combine half-wave partials; finish softmax; bias + relu -> rbuf
      const float z = zph + __shfl_xor(zph, 32, 64);
      acc.x += __shfl_xor(acc.x, 32, 64);
      acc.y += __shfl_xor(acc.y, 32, 64);
      acc.z += __shfl_xor(acc.z, 32, 64);
      acc.w += __shfl_xor(acc.w, 32, 64);
      const float inv = 1.f/(z + EPSV);
      const float4 bv = *reinterpret_cast<const float4*>(bias + cq);
      float4 o;
      o.x = fmaxf(fmaf(acc.x, inv, bv.x), 0.f);
      o.y = fmaxf(fmaf(acc.y, inv, bv.y), 0.f);
      o.z = fmaxf(fmaf(acc.z, inv, bv.z), 0.f);
      o.w = fmaxf(fmaf(acc.w, inv, bv.w), 0.f);
      if (half == 0) *reinterpret_cast<float4*>(&rbuf[local][cq]) = o;
    }
    // pull next node from the block queue
    int nxt = 0;
    if (lane == 0) nxt = atomicAdd(&qhead, 1);
    local = __shfl(nxt, 0, 64);
  }
  __syncthreads();
  gemv_phase<HNEXT>(rbuf, nbase, N, Wn, an_src, an_dst, h_out, es_out, ed_out, pE, pD);
}

// ---------------- Final aggregation (heads=1, no relu) -> d_out ----------------
__launch_bounds__(512, 8)
__global__ void final_agg_kernel(const float* __restrict__ h, const float* __restrict__ es, const float* __restrict__ ed,
                                 const int* __restrict__ row_ptr, const int* __restrict__ csr_src,
                                 const float* __restrict__ bias, float* __restrict__ out, int N){
  __shared__ int   sIdx[8][64];
  __shared__ float sP[8][64];
  const int lane = threadIdx.x & 63;
  const int wid  = threadIdx.x >> 6;
  const int n = blockIdx.x*8 + wid;
  if (n >= N) return;
  const int start = row_ptr[n], end = row_ptr[n+1];
  const float edn = ed[n];
  const int c0 = lane*2;
  float accx=0.f, accy=0.f, z=0.f;
  for (int t0 = start; t0 < end; t0 += 64){
    const int cnt = min(64, end - t0);
    if (lane < cnt){
      const int s = csr_src[t0 + lane];
      sIdx[wid][lane] = s;
      float p0 = es[s] + edn; p0 = (p0>=0.f)? p0 : NEG*p0; p0 = fminf(p0, 80.f);
      sP[wid][lane] = __expf(p0);
    }
    #pragma unroll 8
    for (int e = 0; e < cnt; e++){
      const int s = sIdx[wid][e];
      const float p = sP[wid][e];
      const float2 hv = *reinterpret_cast<const float2*>(h + (size_t)s*D + c0);
      z += p;
      accx = fmaf(p, hv.x, accx);
      accy = fmaf(p, hv.y, accy);
    }
  }
  const float inv = 1.f/(z + EPSV);
  const float ox = fmaf(accx, inv, bias[c0]), oy = fmaf(accy, inv, bias[c0+1]);
  __builtin_nontemporal_store(ox, &out[(size_t)n*D + c0]);
  __builtin_nontemporal_store(oy, &out[(size_t)n*D + c0 + 1]);
}

extern "C" void kernel_launch(void* const* d_in, const int* in_sizes, int n_in,
                              void* d_out, int out_size, void* d_ws, size_t ws_size,
                              hipStream_t stream) {
  const float* x          = (const float*)d_in[0];
  const int*   ei         = (const int*)d_in[1];
  const float* Ws         = (const float*)d_in[2];
  const float* a_src      = (const float*)d_in[3];
  const float* a_dst      = (const float*)d_in[4];
  const float* bs         = (const float*)d_in[5];
  const float* W_last     = (const float*)d_in[6];
  const float* a_src_last = (const float*)d_in[7];
  const float* a_dst_last = (const float*)d_in[8];
  const float* b_last     = (const float*)d_in[9];

  const int N = in_sizes[0]/D;
  const int E = in_sizes[1]/2;
  const int L = in_sizes[2]/(D*D);   // 19 mid layers
  const int* esrc = ei;
  const int* edst = ei + E;

  // workspace layout (double-buffered h/es/ed)
  char* ws = (char*)d_ws;
  float* h0  = (float*)ws;  ws += (size_t)N*D*sizeof(float);
  float* h1  = (float*)ws;  ws += (size_t)N*D*sizeof(float);
  float* es0 = (float*)ws;  ws += (size_t)N*4*sizeof(float);
  float* es1 = (float*)ws;  ws += (size_t)N*4*sizeof(float);
  float* ed0 = (float*)ws;  ws += (size_t)N*4*sizeof(float);
  float* ed1 = (float*)ws;  ws += (size_t)N*4*sizeof(float);
  int* deg     = (int*)ws;  ws += (size_t)N*sizeof(int);
  int* row_ptr = (int*)ws;  ws += (size_t)(N+1)*sizeof(int);
  int* cursor  = (int*)ws;  ws += (size_t)N*sizeof(int);
  int* csr_src = (int*)ws;  ws += (size_t)(E+N)*sizeof(int);

  const int tot = E + N;
  const int gA = (N + NPB - 1)/NPB;   // 500 blocks
  const int gF = (N + 7)/8;           // 1250 blocks (final agg)

  hipMemsetAsync(deg, 0, (size_t)N*sizeof(int), stream);
  // layer 0 linear + folded degree count
  linear0_kernel<<<gA, 512, 0, stream>>>(x, Ws, a_src, a_dst, N, E, edst, deg, h0, es0, ed0);
  scan_kernel<<<1, 1024, 0, stream>>>(deg, N, row_ptr, cursor);
  scatter_kernel<<<(tot+255)/256, 256, 0, stream>>>(esrc, edst, E, N, cursor, csr_src);

  const float *hc = h0, *esc = es0, *edc = ed0;
  float *hn = h1, *esn = es1, *edn = ed1;

  // fused aggregate(l) + linear(l+1), l = 0..L-2
  for (int l = 0; l < L-1; l++){
    fused_kernel<4><<<gA, 512, 0, stream>>>(hc, esc, edc, row_ptr, csr_src,
                                            bs + (size_t)l*D,
                                            Ws + (size_t)(l+1)*D*D, a_src + (size_t)(l+1)*D, a_dst + (size_t)(l+1)*D,
                                            N, hn, esn, edn);
    const float* tf;
    tf = hc;  hc = hn;  hn = (float*)tf;
    tf = esc; esc = esn; esn = (float*)tf;
    tf = edc; edc = edn; edn = (float*)tf;
  }

  // fused aggregate(L-1) + last linear (heads=1)
  fused_kernel<1><<<gA, 512, 0, stream>>>(hc, esc, edc, row_ptr, csr_src,
                                          bs + (size_t)(L-1)*D,
                                          W_last, a_src_last, a_dst_last,
                                          N, hn, esn, edn);
  {
    const float* tf;
    tf = hc;  hc = hn;  hn = (float*)tf;
    tf = esc; esc = esn; esn = (float*)tf;
    tf = edc; edc = edn; edn = (float*)tf;
  }

  // final aggregation (heads=1, no relu) -> d_out
  final_agg_kernel<<<gF, 512, 0, stream>>>(hc, esc, edc, row_ptr, csr_src, b_last, (float*)d_out, N);
}

// Round 9
// 474.211 us; speedup vs baseline: 1.0254x; 1.0254x over previous
//
#include <hip/hip_runtime.h>
#include <hip/hip_bf16.h>
#include <math.h>

#define D 128
#define NEG 0.2f
#define EPSV 1e-16f
#define NPB 16          // nodes per block: one per HALF-WAVE (N=10000 -> exactly 625 blocks)
#define GRP_N 4         // nodes per 128-col group in GEMV (4 groups * 4 = NPB)

// ---------------- CSR build (once per call; graph constant across layers) ----------------
// count is folded into linear0_kernel (saves a dispatch).
__global__ void scan_kernel(const int* __restrict__ deg, int N, int* __restrict__ row_ptr, int* __restrict__ cursor){
  __shared__ int part[1024];
  const int CH = 16;                 // 1024*16 = 16384 >= N
  int t = threadIdx.x;
  int base = t*CH;
  int local[CH]; int s = 0;
  #pragma unroll
  for (int j=0;j<CH;j++){ int idx=base+j; int v = (idx<N)? deg[idx] : 0; local[j]=s; s+=v; }
  part[t]=s; __syncthreads();
  for (int off=1; off<1024; off<<=1){
    int v = (t>=off)? part[t-off] : 0;
    __syncthreads();
    part[t]+=v;
    __syncthreads();
  }
  int cb = (t==0)? 0 : part[t-1];
  #pragma unroll
  for (int j=0;j<CH;j++){ int idx=base+j; if(idx<N){ int r=cb+local[j]; row_ptr[idx]=r; cursor[idx]=r; } }
  if (t==1023) row_ptr[N]=part[1023];
}

__global__ void scatter_kernel(const int* __restrict__ esrc, const int* __restrict__ edst,
                               int E, int N, int* __restrict__ cursor, int* __restrict__ csr_src){
  int i = blockIdx.x*blockDim.x + threadIdx.x;
  int tot = E + N;
  if (i>=tot) return;
  int s, d2;
  if (i<E){ s=esrc[i]; d2=edst[i]; } else { s=i-E; d2=i-E; }
  int pos = atomicAdd(&cursor[d2],1);
  csr_src[pos]=s;
}

// ---------------- GEMV phase: rbuf rows @ W -> h + es/ed ----------------
// 512 threads = 4 col-groups of 128; each group computes GRP_N nodes.
// Per k: 1 coalesced W load feeds GRP_N FMAs per thread. h_out stores are
// non-temporal (consumed next layer mostly by other XCDs).
template<int HNEXT>
__device__ __forceinline__ void gemv_phase(const float (*rbuf)[D], int nbase, int N,
                                           const float* __restrict__ Wn,
                                           const float* __restrict__ av_, const float* __restrict__ bv_,
                                           float* __restrict__ h_out, float* __restrict__ es_out,
                                           float* __restrict__ ed_out, float (*pE)[2], float (*pD)[2]){
  const int t   = threadIdx.x;
  const int col = t & (D-1);
  const int g   = t >> 7;                 // 0..3
  const float av = av_[col], bv = bv_[col];
  const float* __restrict__ r[GRP_N];
  #pragma unroll
  for (int j=0;j<GRP_N;j++) r[j] = rbuf[g*GRP_N + j];
  float acc[GRP_N];
  #pragma unroll
  for (int j=0;j<GRP_N;j++) acc[j]=0.f;

  #pragma unroll 4
  for (int k=0;k<D;k+=4){
    const float w0 = Wn[(size_t)(k+0)*D + col];
    const float w1 = Wn[(size_t)(k+1)*D + col];
    const float w2 = Wn[(size_t)(k+2)*D + col];
    const float w3 = Wn[(size_t)(k+3)*D + col];
    #pragma unroll
    for (int j=0;j<GRP_N;j++){
      const float4 xv = *reinterpret_cast<const float4*>(r[j] + k);
      acc[j] = fmaf(xv.w, w3, fmaf(xv.z, w2, fmaf(xv.y, w1, fmaf(xv.x, w0, acc[j]))));
    }
  }

  if constexpr (HNEXT==4){
    #pragma unroll
    for (int j=0;j<GRP_N;j++){
      const int n = nbase + g*GRP_N + j;
      if (n < N){                          // group-uniform
        __builtin_nontemporal_store(acc[j], &h_out[(size_t)n*D + col]);
        float ps = acc[j]*av, pd = acc[j]*bv;
        #pragma unroll
        for (int off=16; off; off>>=1){ ps += __shfl_xor(ps, off, 32); pd += __shfl_xor(pd, off, 32); }
        if ((col&31)==0){ es_out[n*4 + (col>>5)] = ps; ed_out[n*4 + (col>>5)] = pd; }
      }
    }
  } else {
    const int half = (t>>6)&1;
    #pragma unroll
    for (int j=0;j<GRP_N;j++){
      const int n = nbase + g*GRP_N + j;
      float ps = 0.f, pd = 0.f;
      if (n < N){
        __builtin_nontemporal_store(acc[j], &h_out[(size_t)n*D + col]);
        ps = acc[j]*av; pd = acc[j]*bv;
      }
      #pragma unroll
      for (int off=32; off; off>>=1){ ps += __shfl_xor(ps, off, 64); pd += __shfl_xor(pd, off, 64); }
      if ((t&63)==0){ pE[g*GRP_N+j][half]=ps; pD[g*GRP_N+j][half]=pd; }
    }
    __syncthreads();
    if (t < NPB){
      const int n = nbase + t;
      if (n < N){
        es_out[n] = pE[t][0]+pE[t][1];
        ed_out[n] = pD[t][0]+pD[t][1];
      }
    }
  }
}

// ---------------- Layer-0 linear (+ folded CSR degree count) ----------------
__launch_bounds__(512, 4)
__global__ void linear0_kernel(const float* __restrict__ x, const float* __restrict__ Wn,
                               const float* __restrict__ an_src, const float* __restrict__ an_dst,
                               int N, int E, const int* __restrict__ edst, int* __restrict__ deg,
                               float* __restrict__ h_out, float* __restrict__ es_out, float* __restrict__ ed_out){
  __shared__ float rbuf[NPB][D];
  __shared__ float pE[NPB][2], pD[NPB][2];
  const int t = threadIdx.x;
  const int nbase = blockIdx.x*NPB;
  // folded CSR count (deg pre-zeroed by memsetAsync)
  {
    const int gid = blockIdx.x*512 + t;
    const int gs  = gridDim.x*512;
    const int tot = E + N;
    for (int i = gid; i < tot; i += gs){
      const int d2 = (i < E) ? edst[i] : (i - E);
      atomicAdd(&deg[d2], 1);
    }
  }
  {
    // 16 rows * 32 float4 = 512 loads, exactly one per thread
    const int row = t >> 5;
    const int cc  = (t & 31) * 4;
    int n = nbase + row; if (n > N-1) n = N-1;
    const float4 v = *reinterpret_cast<const float4*>(x + (size_t)n*D + cc);
    *reinterpret_cast<float4*>(&rbuf[row][cc]) = v;
  }
  __syncthreads();
  gemv_phase<4>(rbuf, nbase, N, Wn, an_src, an_dst, h_out, es_out, ed_out, pE, pD);
}

// ---------------- Fused: aggregate(layer l, heads=4) + linear(layer l+1) ----------------
// Aggregate: ONE NODE PER HALF-WAVE (16 concurrent node streams per block -> 2x MLP
// vs node-per-wave). Per 32-edge tile: phase A lanes gather csr+es, exp -> sIdx (s*D)
// + packed sP[4] (half-wave-private LDS, ordered by lgkmcnt within the wave, no barrier).
// Phase B: one edge per iteration; 32 lanes x float4 = the full 512B h row in one
// instruction; every lane accumulates every edge -> z and acc complete with NO shuffles.
// Single-pass softmax (exp clamped at 80). Result row (bias+relu) -> rbuf.
// GEMV: NPB aggregated rows @ next layer's W + attention dots.
template<int HNEXT>
__launch_bounds__(512, 4)
__global__ void fused_kernel(const float* __restrict__ h, const float* __restrict__ es, const float* __restrict__ ed,
                             const int* __restrict__ row_ptr, const int* __restrict__ csr_src,
                             const float* __restrict__ bias,
                             const float* __restrict__ Wn, const float* __restrict__ an_src, const float* __restrict__ an_dst,
                             int N, float* __restrict__ h_out, float* __restrict__ es_out, float* __restrict__ ed_out){
  __shared__ int   sIdx[NPB][32];      // 2 KB  (premultiplied: s*D)
  __shared__ float sP[NPB][32][4];     // 8 KB  (p per head, packed float4 per edge)
  __shared__ float rbuf[NPB][D];       // 8 KB
  __shared__ float pE[NPB][2], pD[NPB][2];
  const int t = threadIdx.x;
  const int hw  = t >> 5;            // half-wave id 0..15 == local node
  const int l32 = t & 31;
  const int cq   = l32 * 4;          // my 4 channels
  const int myh4 = l32 >> 3;         // my head
  const int nbase = blockIdx.x*NPB;
  const int n = nbase + hw;

  if (n < N){
    const int start = row_ptr[n], end = row_ptr[n+1];
    const float4 edv = *reinterpret_cast<const float4*>(ed + (size_t)n*4);
    float4 acc = make_float4(0.f,0.f,0.f,0.f);
    float z = 0.f;

    for (int t0 = start; t0 < end; t0 += 32){
      const int cnt = min(32, end - t0);
      // --- phase A: edge-parallel p computation (zero-padded beyond cnt) ---
      {
        int sOff = 0; float p0=0.f,p1=0.f,p2=0.f,p3=0.f;
        if (l32 < cnt){
          const int s = csr_src[t0 + l32];
          sOff = s*D;
          const float4 e4 = *reinterpret_cast<const float4*>(es + (size_t)s*4);
          float q0 = e4.x + edv.x; q0 = (q0>=0.f)? q0 : NEG*q0; q0 = fminf(q0, 80.f);
          float q1 = e4.y + edv.y; q1 = (q1>=0.f)? q1 : NEG*q1; q1 = fminf(q1, 80.f);
          float q2 = e4.z + edv.z; q2 = (q2>=0.f)? q2 : NEG*q2; q2 = fminf(q2, 80.f);
          float q3 = e4.w + edv.w; q3 = (q3>=0.f)? q3 : NEG*q3; q3 = fminf(q3, 80.f);
          p0 = __expf(q0); p1 = __expf(q1); p2 = __expf(q2); p3 = __expf(q3);
        }
        sIdx[hw][l32] = sOff;
        *reinterpret_cast<float4*>(&sP[hw][l32][0]) = make_float4(p0,p1,p2,p3);
      }
      // --- phase B: one edge per iteration; full h row in one instruction ---
      #pragma unroll 8
      for (int e = 0; e < cnt; e++){
        const int   off = sIdx[hw][e];         // LDS broadcast
        const float p   = sP[hw][e][myh4];     // 4-address LDS broadcast
        const float4 hv = *reinterpret_cast<const float4*>(h + (size_t)off + cq);
        z += p;
        acc.x = fmaf(p, hv.x, acc.x);
        acc.y = fmaf(p, hv.y, acc.y);
        acc.z = fmaf(p, hv.z, acc.z);
        acc.w = fmaf(p, hv.w, acc.w);
      }
    }
    // finish softmax; bias + relu -> rbuf (z identical in every lane; no shuffles)
    const float inv = 1.f/(z + EPSV);
    const float4 bv = *reinterpret_cast<const float4*>(bias + cq);
    float4 o;
    o.x = fmaxf(fmaf(acc.x, inv, bv.x), 0.f);
    o.y = fmaxf(fmaf(acc.y, inv, bv.y), 0.f);
    o.z = fmaxf(fmaf(acc.z, inv, bv.z), 0.f);
    o.w = fmaxf(fmaf(acc.w, inv, bv.w), 0.f);
    *reinterpret_cast<float4*>(&rbuf[hw][cq]) = o;
  } else {
    *reinterpret_cast<float4*>(&rbuf[hw][cq]) = make_float4(0.f,0.f,0.f,0.f);
  }
  __syncthreads();
  gemv_phase<HNEXT>(rbuf, nbase, N, Wn, an_src, an_dst, h_out, es_out, ed_out, pE, pD);
}

// ---------------- Final aggregation (heads=1, no relu) -> d_out ----------------
// Same half-wave-per-node structure; p is head-less (scalar), no shuffles needed.
__launch_bounds__(512, 8)
__global__ void final_agg_kernel(const float* __restrict__ h, const float* __restrict__ es, const float* __restrict__ ed,
                                 const int* __restrict__ row_ptr, const int* __restrict__ csr_src,
                                 const float* __restrict__ bias, float* __restrict__ out, int N){
  __shared__ int   sIdx[NPB][32];
  __shared__ float sP[NPB][32];
  const int t = threadIdx.x;
  const int hw  = t >> 5;
  const int l32 = t & 31;
  const int cq  = l32 * 4;
  const int n = blockIdx.x*NPB + hw;
  if (n >= N) return;
  const int start = row_ptr[n], end = row_ptr[n+1];
  const float edn = ed[n];
  float4 acc = make_float4(0.f,0.f,0.f,0.f);
  float z = 0.f;
  for (int t0 = start; t0 < end; t0 += 32){
    const int cnt = min(32, end - t0);
    {
      int sOff = 0; float p0 = 0.f;
      if (l32 < cnt){
        const int s = csr_src[t0 + l32];
        sOff = s*D;
        float q0 = es[s] + edn; q0 = (q0>=0.f)? q0 : NEG*q0; q0 = fminf(q0, 80.f);
        p0 = __expf(q0);
      }
      sIdx[hw][l32] = sOff;
      sP[hw][l32] = p0;
    }
    #pragma unroll 8
    for (int e = 0; e < cnt; e++){
      const int   off = sIdx[hw][e];
      const float p   = sP[hw][e];
      const float4 hv = *reinterpret_cast<const float4*>(h + (size_t)off + cq);
      z += p;
      acc.x = fmaf(p, hv.x, acc.x);
      acc.y = fmaf(p, hv.y, acc.y);
      acc.z = fmaf(p, hv.z, acc.z);
      acc.w = fmaf(p, hv.w, acc.w);
    }
  }
  const float inv = 1.f/(z + EPSV);
  const float4 bv = *reinterpret_cast<const float4*>(bias + cq);
  float4 o;
  o.x = fmaf(acc.x, inv, bv.x);
  o.y = fmaf(acc.y, inv, bv.y);
  o.z = fmaf(acc.z, inv, bv.z);
  o.w = fmaf(acc.w, inv, bv.w);
  *reinterpret_cast<float4*>(&out[(size_t)n*D + cq]) = o;
}

extern "C" void kernel_launch(void* const* d_in, const int* in_sizes, int n_in,
                              void* d_out, int out_size, void* d_ws, size_t ws_size,
                              hipStream_t stream) {
  const float* x          = (const float*)d_in[0];
  const int*   ei         = (const int*)d_in[1];
  const float* Ws         = (const float*)d_in[2];
  const float* a_src      = (const float*)d_in[3];
  const float* a_dst      = (const float*)d_in[4];
  const float* bs         = (const float*)d_in[5];
  const float* W_last     = (const float*)d_in[6];
  const float* a_src_last = (const float*)d_in[7];
  const float* a_dst_last = (const float*)d_in[8];
  const float* b_last     = (const float*)d_in[9];

  const int N = in_sizes[0]/D;
  const int E = in_sizes[1]/2;
  const int L = in_sizes[2]/(D*D);   // 19 mid layers
  const int* esrc = ei;
  const int* edst = ei + E;

  // workspace layout (double-buffered h/es/ed)
  char* ws = (char*)d_ws;
  float* h0  = (float*)ws;  ws += (size_t)N*D*sizeof(float);
  float* h1  = (float*)ws;  ws += (size_t)N*D*sizeof(float);
  float* es0 = (float*)ws;  ws += (size_t)N*4*sizeof(float);
  float* es1 = (float*)ws;  ws += (size_t)N*4*sizeof(float);
  float* ed0 = (float*)ws;  ws += (size_t)N*4*sizeof(float);
  float* ed1 = (float*)ws;  ws += (size_t)N*4*sizeof(float);
  int* deg     = (int*)ws;  ws += (size_t)N*sizeof(int);
  int* row_ptr = (int*)ws;  ws += (size_t)(N+1)*sizeof(int);
  int* cursor  = (int*)ws;  ws += (size_t)N*sizeof(int);
  int* csr_src = (int*)ws;  ws += (size_t)(E+N)*sizeof(int);

  const int tot = E + N;
  const int gA = (N + NPB - 1)/NPB;   // 625 blocks

  hipMemsetAsync(deg, 0, (size_t)N*sizeof(int), stream);
  // layer 0 linear + folded degree count
  linear0_kernel<<<gA, 512, 0, stream>>>(x, Ws, a_src, a_dst, N, E, edst, deg, h0, es0, ed0);
  scan_kernel<<<1, 1024, 0, stream>>>(deg, N, row_ptr, cursor);
  scatter_kernel<<<(tot+255)/256, 256, 0, stream>>>(esrc, edst, E, N, cursor, csr_src);

  const float *hc = h0, *esc = es0, *edc = ed0;
  float *hn = h1, *esn = es1, *edn = ed1;

  // fused aggregate(l) + linear(l+1), l = 0..L-2
  for (int l = 0; l < L-1; l++){
    fused_kernel<4><<<gA, 512, 0, stream>>>(hc, esc, edc, row_ptr, csr_src,
                                            bs + (size_t)l*D,
                                            Ws + (size_t)(l+1)*D*D, a_src + (size_t)(l+1)*D, a_dst + (size_t)(l+1)*D,
                                            N, hn, esn, edn);
    const float* tf;
    tf = hc;  hc = hn;  hn = (float*)tf;
    tf = esc; esc = esn; esn = (float*)tf;
    tf = edc; edc = edn; edn = (float*)tf;
  }

  // fused aggregate(L-1) + last linear (heads=1)
  fused_kernel<1><<<gA, 512, 0, stream>>>(hc, esc, edc, row_ptr, csr_src,
                                          bs + (size_t)(L-1)*D,
                                          W_last, a_src_last, a_dst_last,
                                          N, hn, esn, edn);
  {
    const float* tf;
    tf = hc;  hc = hn;  hn = (float*)tf;
    tf = esc; esc = esn; esn = (float*)tf;
    tf = edc; edc = edn; edn = (float*)tf;
  }

  // final aggregation (heads=1, no relu) -> d_out
  final_agg_kernel<<<gA, 512, 0, stream>>>(hc, esc, edc, row_ptr, csr_src, b_last, (float*)d_out, N);
}

// Round 10
// 433.448 us; speedup vs baseline: 1.1219x; 1.0940x over previous
//
#include <hip/hip_runtime.h>
#include <hip/hip_bf16.h>
#include <math.h>

#define D 128
#define NEG 0.2f
#define EPSV 1e-16f
#define NPB 8           // nodes per block: one per HALF-WAVE, 256-thr blocks
                        // N=10000 -> 1250 blocks (~4.9/CU, dynamic balancing)
#define GRP_N 4         // nodes per 128-col group in GEMV (2 groups * 4 = NPB)

// ---------------- CSR build (once per call; graph constant across layers) ----------------
// count is folded into linear0_kernel (saves a dispatch).
__global__ void scan_kernel(const int* __restrict__ deg, int N, int* __restrict__ row_ptr, int* __restrict__ cursor){
  __shared__ int part[1024];
  const int CH = 16;                 // 1024*16 = 16384 >= N
  int t = threadIdx.x;
  int base = t*CH;
  int local[CH]; int s = 0;
  #pragma unroll
  for (int j=0;j<CH;j++){ int idx=base+j; int v = (idx<N)? deg[idx] : 0; local[j]=s; s+=v; }
  part[t]=s; __syncthreads();
  for (int off=1; off<1024; off<<=1){
    int v = (t>=off)? part[t-off] : 0;
    __syncthreads();
    part[t]+=v;
    __syncthreads();
  }
  int cb = (t==0)? 0 : part[t-1];
  #pragma unroll
  for (int j=0;j<CH;j++){ int idx=base+j; if(idx<N){ int r=cb+local[j]; row_ptr[idx]=r; cursor[idx]=r; } }
  if (t==1023) row_ptr[N]=part[1023];
}

__global__ void scatter_kernel(const int* __restrict__ esrc, const int* __restrict__ edst,
                               int E, int N, int* __restrict__ cursor, int* __restrict__ csr_src){
  int i = blockIdx.x*blockDim.x + threadIdx.x;
  int tot = E + N;
  if (i>=tot) return;
  int s, d2;
  if (i<E){ s=esrc[i]; d2=edst[i]; } else { s=i-E; d2=i-E; }
  int pos = atomicAdd(&cursor[d2],1);
  csr_src[pos]=s;
}

// ---------------- GEMV phase: rbuf rows @ W -> h + es/ed ----------------
// 256 threads = 2 col-groups of 128; each group computes GRP_N nodes.
// Per k: 1 W load (L1-shared across the 2 groups) feeds GRP_N FMAs per thread.
// h_out stores are non-temporal (consumed next layer mostly by other XCDs).
template<int HNEXT>
__device__ __forceinline__ void gemv_phase(const float (*rbuf)[D], int nbase, int N,
                                           const float* __restrict__ Wn,
                                           const float* __restrict__ av_, const float* __restrict__ bv_,
                                           float* __restrict__ h_out, float* __restrict__ es_out,
                                           float* __restrict__ ed_out, float (*pE)[2], float (*pD)[2]){
  const int t   = threadIdx.x;
  const int col = t & (D-1);
  const int g   = t >> 7;                 // 0..1
  const float av = av_[col], bv = bv_[col];
  const float* __restrict__ r[GRP_N];
  #pragma unroll
  for (int j=0;j<GRP_N;j++) r[j] = rbuf[g*GRP_N + j];
  float acc[GRP_N];
  #pragma unroll
  for (int j=0;j<GRP_N;j++) acc[j]=0.f;

  #pragma unroll 4
  for (int k=0;k<D;k+=4){
    const float w0 = Wn[(size_t)(k+0)*D + col];
    const float w1 = Wn[(size_t)(k+1)*D + col];
    const float w2 = Wn[(size_t)(k+2)*D + col];
    const float w3 = Wn[(size_t)(k+3)*D + col];
    #pragma unroll
    for (int j=0;j<GRP_N;j++){
      const float4 xv = *reinterpret_cast<const float4*>(r[j] + k);
      acc[j] = fmaf(xv.w, w3, fmaf(xv.z, w2, fmaf(xv.y, w1, fmaf(xv.x, w0, acc[j]))));
    }
  }

  if constexpr (HNEXT==4){
    #pragma unroll
    for (int j=0;j<GRP_N;j++){
      const int n = nbase + g*GRP_N + j;
      if (n < N){                          // group-uniform
        __builtin_nontemporal_store(acc[j], &h_out[(size_t)n*D + col]);
        float ps = acc[j]*av, pd = acc[j]*bv;
        #pragma unroll
        for (int off=16; off; off>>=1){ ps += __shfl_xor(ps, off, 32); pd += __shfl_xor(pd, off, 32); }
        if ((col&31)==0){ es_out[n*4 + (col>>5)] = ps; ed_out[n*4 + (col>>5)] = pd; }
      }
    }
  } else {
    const int half = (t>>6)&1;
    #pragma unroll
    for (int j=0;j<GRP_N;j++){
      const int n = nbase + g*GRP_N + j;
      float ps = 0.f, pd = 0.f;
      if (n < N){
        __builtin_nontemporal_store(acc[j], &h_out[(size_t)n*D + col]);
        ps = acc[j]*av; pd = acc[j]*bv;
      }
      #pragma unroll
      for (int off=32; off; off>>=1){ ps += __shfl_xor(ps, off, 64); pd += __shfl_xor(pd, off, 64); }
      if ((t&63)==0){ pE[g*GRP_N+j][half]=ps; pD[g*GRP_N+j][half]=pd; }
    }
    __syncthreads();
    if (t < NPB){
      const int n = nbase + t;
      if (n < N){
        es_out[n] = pE[t][0]+pE[t][1];
        ed_out[n] = pD[t][0]+pD[t][1];
      }
    }
  }
}

// ---------------- Layer-0 linear (+ folded CSR degree count) ----------------
__launch_bounds__(256, 4)
__global__ void linear0_kernel(const float* __restrict__ x, const float* __restrict__ Wn,
                               const float* __restrict__ an_src, const float* __restrict__ an_dst,
                               int N, int E, const int* __restrict__ edst, int* __restrict__ deg,
                               float* __restrict__ h_out, float* __restrict__ es_out, float* __restrict__ ed_out){
  __shared__ float rbuf[NPB][D];
  __shared__ float pE[NPB][2], pD[NPB][2];
  const int t = threadIdx.x;
  const int nbase = blockIdx.x*NPB;
  // folded CSR count (deg pre-zeroed by memsetAsync)
  {
    const int gid = blockIdx.x*256 + t;
    const int gs  = gridDim.x*256;
    const int tot = E + N;
    for (int i = gid; i < tot; i += gs){
      const int d2 = (i < E) ? edst[i] : (i - E);
      atomicAdd(&deg[d2], 1);
    }
  }
  {
    // 8 rows * 32 float4 = 256 loads, exactly one per thread
    const int row = t >> 5;
    const int cc  = (t & 31) * 4;
    int n = nbase + row; if (n > N-1) n = N-1;
    const float4 v = *reinterpret_cast<const float4*>(x + (size_t)n*D + cc);
    *reinterpret_cast<float4*>(&rbuf[row][cc]) = v;
  }
  __syncthreads();
  gemv_phase<4>(rbuf, nbase, N, Wn, an_src, an_dst, h_out, es_out, ed_out, pE, pD);
}

// ---------------- Fused: aggregate(layer l, heads=4) + linear(layer l+1) ----------------
// Aggregate: ONE NODE PER HALF-WAVE (8 node streams/block; 1250 small blocks give the
// HW scheduler dynamic cross-CU balancing -- the 625-block version had a 3-vs-2
// blocks/CU quantization tail). Per 32-edge tile: phase A lanes gather csr+es, exp ->
// sIdx (s*D) + packed sP[4] (half-wave-private LDS, lgkmcnt-ordered, no barrier).
// Phase B: one edge per iteration; 32 lanes x float4 = the full 512B h row in one
// instruction; z and acc complete with NO shuffles. Single-pass softmax (exp<=e^80).
// GEMV: NPB aggregated rows @ next layer's W + attention dots.
template<int HNEXT>
__launch_bounds__(256, 4)
__global__ void fused_kernel(const float* __restrict__ h, const float* __restrict__ es, const float* __restrict__ ed,
                             const int* __restrict__ row_ptr, const int* __restrict__ csr_src,
                             const float* __restrict__ bias,
                             const float* __restrict__ Wn, const float* __restrict__ an_src, const float* __restrict__ an_dst,
                             int N, float* __restrict__ h_out, float* __restrict__ es_out, float* __restrict__ ed_out){
  __shared__ int   sIdx[NPB][32];      // 1 KB  (premultiplied: s*D)
  __shared__ float sP[NPB][32][4];     // 4 KB  (p per head, packed float4 per edge)
  __shared__ float rbuf[NPB][D];       // 4 KB
  __shared__ float pE[NPB][2], pD[NPB][2];
  const int t = threadIdx.x;
  const int hw  = t >> 5;            // half-wave id 0..7 == local node
  const int l32 = t & 31;
  const int cq   = l32 * 4;          // my 4 channels
  const int myh4 = l32 >> 3;         // my head
  const int nbase = blockIdx.x*NPB;
  const int n = nbase + hw;

  if (n < N){
    const int start = row_ptr[n], end = row_ptr[n+1];
    const float4 edv = *reinterpret_cast<const float4*>(ed + (size_t)n*4);
    float4 acc = make_float4(0.f,0.f,0.f,0.f);
    float z = 0.f;

    for (int t0 = start; t0 < end; t0 += 32){
      const int cnt = min(32, end - t0);
      // --- phase A: edge-parallel p computation (zero-padded beyond cnt) ---
      {
        int sOff = 0; float p0=0.f,p1=0.f,p2=0.f,p3=0.f;
        if (l32 < cnt){
          const int s = csr_src[t0 + l32];
          sOff = s*D;
          const float4 e4 = *reinterpret_cast<const float4*>(es + (size_t)s*4);
          float q0 = e4.x + edv.x; q0 = (q0>=0.f)? q0 : NEG*q0; q0 = fminf(q0, 80.f);
          float q1 = e4.y + edv.y; q1 = (q1>=0.f)? q1 : NEG*q1; q1 = fminf(q1, 80.f);
          float q2 = e4.z + edv.z; q2 = (q2>=0.f)? q2 : NEG*q2; q2 = fminf(q2, 80.f);
          float q3 = e4.w + edv.w; q3 = (q3>=0.f)? q3 : NEG*q3; q3 = fminf(q3, 80.f);
          p0 = __expf(q0); p1 = __expf(q1); p2 = __expf(q2); p3 = __expf(q3);
        }
        sIdx[hw][l32] = sOff;
        *reinterpret_cast<float4*>(&sP[hw][l32][0]) = make_float4(p0,p1,p2,p3);
      }
      // --- phase B: one edge per iteration; full h row in one instruction ---
      #pragma unroll 8
      for (int e = 0; e < cnt; e++){
        const int   off = sIdx[hw][e];         // LDS broadcast
        const float p   = sP[hw][e][myh4];     // 4-address LDS broadcast
        const float4 hv = *reinterpret_cast<const float4*>(h + (size_t)off + cq);
        z += p;
        acc.x = fmaf(p, hv.x, acc.x);
        acc.y = fmaf(p, hv.y, acc.y);
        acc.z = fmaf(p, hv.z, acc.z);
        acc.w = fmaf(p, hv.w, acc.w);
      }
    }
    // finish softmax; bias + relu -> rbuf (z identical in every lane; no shuffles)
    const float inv = 1.f/(z + EPSV);
    const float4 bv = *reinterpret_cast<const float4*>(bias + cq);
    float4 o;
    o.x = fmaxf(fmaf(acc.x, inv, bv.x), 0.f);
    o.y = fmaxf(fmaf(acc.y, inv, bv.y), 0.f);
    o.z = fmaxf(fmaf(acc.z, inv, bv.z), 0.f);
    o.w = fmaxf(fmaf(acc.w, inv, bv.w), 0.f);
    *reinterpret_cast<float4*>(&rbuf[hw][cq]) = o;
  } else {
    *reinterpret_cast<float4*>(&rbuf[hw][cq]) = make_float4(0.f,0.f,0.f,0.f);
  }
  __syncthreads();
  gemv_phase<HNEXT>(rbuf, nbase, N, Wn, an_src, an_dst, h_out, es_out, ed_out, pE, pD);
}

// ---------------- Final aggregation (heads=1, no relu) -> d_out ----------------
__launch_bounds__(256, 4)
__global__ void final_agg_kernel(const float* __restrict__ h, const float* __restrict__ es, const float* __restrict__ ed,
                                 const int* __restrict__ row_ptr, const int* __restrict__ csr_src,
                                 const float* __restrict__ bias, float* __restrict__ out, int N){
  __shared__ int   sIdx[NPB][32];
  __shared__ float sP[NPB][32];
  const int t = threadIdx.x;
  const int hw  = t >> 5;
  const int l32 = t & 31;
  const int cq  = l32 * 4;
  const int n = blockIdx.x*NPB + hw;
  if (n >= N) return;
  const int start = row_ptr[n], end = row_ptr[n+1];
  const float edn = ed[n];
  float4 acc = make_float4(0.f,0.f,0.f,0.f);
  float z = 0.f;
  for (int t0 = start; t0 < end; t0 += 32){
    const int cnt = min(32, end - t0);
    {
      int sOff = 0; float p0 = 0.f;
      if (l32 < cnt){
        const int s = csr_src[t0 + l32];
        sOff = s*D;
        float q0 = es[s] + edn; q0 = (q0>=0.f)? q0 : NEG*q0; q0 = fminf(q0, 80.f);
        p0 = __expf(q0);
      }
      sIdx[hw][l32] = sOff;
      sP[hw][l32] = p0;
    }
    #pragma unroll 8
    for (int e = 0; e < cnt; e++){
      const int   off = sIdx[hw][e];
      const float p   = sP[hw][e];
      const float4 hv = *reinterpret_cast<const float4*>(h + (size_t)off + cq);
      z += p;
      acc.x = fmaf(p, hv.x, acc.x);
      acc.y = fmaf(p, hv.y, acc.y);
      acc.z = fmaf(p, hv.z, acc.z);
      acc.w = fmaf(p, hv.w, acc.w);
    }
  }
  const float inv = 1.f/(z + EPSV);
  const float4 bv = *reinterpret_cast<const float4*>(bias + cq);
  float4 o;
  o.x = fmaf(acc.x, inv, bv.x);
  o.y = fmaf(acc.y, inv, bv.y);
  o.z = fmaf(acc.z, inv, bv.z);
  o.w = fmaf(acc.w, inv, bv.w);
  *reinterpret_cast<float4*>(&out[(size_t)n*D + cq]) = o;
}

extern "C" void kernel_launch(void* const* d_in, const int* in_sizes, int n_in,
                              void* d_out, int out_size, void* d_ws, size_t ws_size,
                              hipStream_t stream) {
  const float* x          = (const float*)d_in[0];
  const int*   ei         = (const int*)d_in[1];
  const float* Ws         = (const float*)d_in[2];
  const float* a_src      = (const float*)d_in[3];
  const float* a_dst      = (const float*)d_in[4];
  const float* bs         = (const float*)d_in[5];
  const float* W_last     = (const float*)d_in[6];
  const float* a_src_last = (const float*)d_in[7];
  const float* a_dst_last = (const float*)d_in[8];
  const float* b_last     = (const float*)d_in[9];

  const int N = in_sizes[0]/D;
  const int E = in_sizes[1]/2;
  const int L = in_sizes[2]/(D*D);   // 19 mid layers
  const int* esrc = ei;
  const int* edst = ei + E;

  // workspace layout (double-buffered h/es/ed)
  char* ws = (char*)d_ws;
  float* h0  = (float*)ws;  ws += (size_t)N*D*sizeof(float);
  float* h1  = (float*)ws;  ws += (size_t)N*D*sizeof(float);
  float* es0 = (float*)ws;  ws += (size_t)N*4*sizeof(float);
  float* es1 = (float*)ws;  ws += (size_t)N*4*sizeof(float);
  float* ed0 = (float*)ws;  ws += (size_t)N*4*sizeof(float);
  float* ed1 = (float*)ws;  ws += (size_t)N*4*sizeof(float);
  int* deg     = (int*)ws;  ws += (size_t)N*sizeof(int);
  int* row_ptr = (int*)ws;  ws += (size_t)(N+1)*sizeof(int);
  int* cursor  = (int*)ws;  ws += (size_t)N*sizeof(int);
  int* csr_src = (int*)ws;  ws += (size_t)(E+N)*sizeof(int);

  const int tot = E + N;
  const int gA = (N + NPB - 1)/NPB;   // 1250 blocks

  hipMemsetAsync(deg, 0, (size_t)N*sizeof(int), stream);
  // layer 0 linear + folded degree count
  linear0_kernel<<<gA, 256, 0, stream>>>(x, Ws, a_src, a_dst, N, E, edst, deg, h0, es0, ed0);
  scan_kernel<<<1, 1024, 0, stream>>>(deg, N, row_ptr, cursor);
  scatter_kernel<<<(tot+255)/256, 256, 0, stream>>>(esrc, edst, E, N, cursor, csr_src);

  const float *hc = h0, *esc = es0, *edc = ed0;
  float *hn = h1, *esn = es1, *edn = ed1;

  // fused aggregate(l) + linear(l+1), l = 0..L-2
  for (int l = 0; l < L-1; l++){
    fused_kernel<4><<<gA, 256, 0, stream>>>(hc, esc, edc, row_ptr, csr_src,
                                            bs + (size_t)l*D,
                                            Ws + (size_t)(l+1)*D*D, a_src + (size_t)(l+1)*D, a_dst + (size_t)(l+1)*D,
                                            N, hn, esn, edn);
    const float* tf;
    tf = hc;  hc = hn;  hn = (float*)tf;
    tf = esc; esc = esn; esn = (float*)tf;
    tf = edc; edc = edn; edn = (float*)tf;
  }

  // fused aggregate(L-1) + last linear (heads=1)
  fused_kernel<1><<<gA, 256, 0, stream>>>(hc, esc, edc, row_ptr, csr_src,
                                          bs + (size_t)(L-1)*D,
                                          W_last, a_src_last, a_dst_last,
                                          N, hn, esn, edn);
  {
    const float* tf;
    tf = hc;  hc = hn;  hn = (float*)tf;
    tf = esc; esc = esn; esn = (float*)tf;
    tf = edc; edc = edn; edn = (float*)tf;
  }

  // final aggregation (heads=1, no relu) -> d_out
  final_agg_kernel<<<gA, 256, 0, stream>>>(hc, esc, edc, row_ptr, csr_src, b_last, (float*)d_out, N);
}